// Round 14
// baseline (892.243 us; speedup 1.0000x reference)
//
#include <hip/hip_runtime.h>
#include <hip/hip_bf16.h>

#define T_STEPS 512
#define BATCH   2048
#define ISZ     128
#define HSZ     64
#define VSZ     128
#define ZSZ     192   // I + H

#define MBLK    8     // batch rows per block -> 256 blocks
#define ATHREADS 512  // 4 P-waves + 4 X-waves

typedef __attribute__((ext_vector_type(8))) short bf16x8;
typedef __attribute__((ext_vector_type(4))) float f32x4;
typedef __attribute__((ext_vector_type(4))) unsigned short u16x4;
typedef __attribute__((ext_vector_type(8))) unsigned short u16x8;

__device__ __forceinline__ unsigned short f2bf(float x) {
  union { float f; unsigned int u; } v; v.f = x;
  unsigned int u = v.u;
  unsigned int r = (u + 0x7fffu + ((u >> 16) & 1u)) >> 16;  // RNE
  return (unsigned short)r;
}

__device__ __forceinline__ unsigned short f2bf_hw(float x) {
  __hip_bfloat16 b = __float2bfloat16(x);
  return *reinterpret_cast<unsigned short*>(&b);
}

// branch-free, NaN-safe at +/-inf (validated rounds 8-13)
__device__ __forceinline__ float fsig(float x) {
  float e = __expf(-x);
  return __builtin_amdgcn_rcpf(1.0f + e);
}
__device__ __forceinline__ float ftanh2(float x) {
  float e = __expf(-2.0f * x);
  return __builtin_amdgcn_rcpf(1.0f + e) * 2.0f - 1.0f;
}

__device__ __forceinline__ void stage16(const void* g, void* l) {
  __builtin_amdgcn_global_load_lds(
      (const __attribute__((address_space(1))) void*)g,
      (__attribute__((address_space(3))) void*)l, 16, 0, 0);
}

// == Fused kernel: P (h-chain) + X (DMA, x-GEMM, out-proj+softmax+probs store) =
__global__ __launch_bounds__(ATHREADS, 1) void lstm_rec(
    const float* __restrict__ x,
    const float* __restrict__ h0,
    const float* __restrict__ c0,
    const float* __restrict__ Wf,  const float* __restrict__ bf_,
    const float* __restrict__ Wif, const float* __restrict__ bif_,
    const float* __restrict__ Wic, const float* __restrict__ bic_,
    const float* __restrict__ Wo,  const float* __restrict__ bo_,
    const float* __restrict__ Wout, const float* __restrict__ bout_,
    float* __restrict__ out)
{
  // gbuf[slot4][xw4][(g*4+lkg)16][col8][4e] f32 — compressed C-frags, bias added
  __shared__ __attribute__((aligned(16))) float gbuf[4][4][512];
  // xbuf: 7-slot ring of x tiles [8 rows][512B], swizzled content (DMA-staged)
  __shared__ __attribute__((aligned(16))) float xbuf[7][1024];
  // hbuf: [slot2][row16][col64] bf16, XOR-swizzled ((row&7)<<4 on bytes)
  __shared__ __attribute__((aligned(16))) unsigned short hbuf[2 * 16 * 64];
  // Wout in LDS: [row128][col64] bf16, byte ^((row&7)<<4) — r9-validated pattern
  __shared__ __attribute__((aligned(16))) unsigned short wout_lds[128 * 64];
  __shared__ __attribute__((aligned(16))) float bias_lds[128];

  const int tid  = threadIdx.x;
  const int wv   = tid >> 6;     // 0..3 = P, 4..7 = X
  const int ln   = tid & 63;
  const int lrow = ln & 15;
  const int lkg  = ln >> 4;
  const int b0   = blockIdx.x * MBLK;
  const int swz  = (lrow & 7) << 4;

  // zero hbuf (rows 8..15 stay zero forever)
  for (int i = tid; i < 2 * 16 * 64; i += ATHREADS) hbuf[i] = 0;
  __syncthreads();
  if (tid < 128) {   // stage h0 rows 0..7, swizzled, packed b64
    const int r = tid >> 4, cb = tid & 15;
    f32x4 hv = *(const f32x4*)&h0[(b0 + r) * HSZ + cb * 4];
    u16x4 pk;
#pragma unroll
    for (int j = 0; j < 4; ++j) pk[j] = f2bf(hv[j]);
    *(u16x4*)((char*)hbuf + r * 128 + ((cb * 8) ^ ((r & 7) << 4))) = pk;
  }
  // stage Wout (bf16, swizzled) + bout into LDS (visible after barrier (B))
  for (int u = tid; u < 1024; u += ATHREADS) {   // 1024 units of 16B
    const int r = u >> 3, cg = u & 7;
    const float* src = Wout + r * HSZ + cg * 8;
    u16x8 pk;
#pragma unroll
    for (int j = 0; j < 8; ++j) pk[j] = f2bf(src[j]);
    *(u16x8*)((char*)wout_lds + r * 128 + ((cg * 16) ^ ((r & 7) << 4))) = pk;
  }
  if (tid < 128) bias_lds[tid] = bout_[tid];

  const float* Wg_[4] = {Wf, Wif, Wic, Wo};
  const float* bg_[4] = {bf_, bif_, bic_, bo_};
  const size_t probs_elems = (size_t)T_STEPS * BATCH * VSZ;

  if (wv < 4) {
    // ========== P-wave: minimal h-chain (r10/r13 form, unchanged) ==========
    const int hcol = 16 * wv + lrow;

    bf16x8 fragWh[4][2];
#pragma unroll
    for (int g = 0; g < 4; ++g)
#pragma unroll
      for (int kf = 0; kf < 2; ++kf) {
        const float* p = Wg_[g] + hcol * ZSZ + ISZ + kf * 32 + 8 * lkg;
        bf16x8 f;
#pragma unroll
        for (int e = 0; e < 8; ++e) f[e] = (short)f2bf(p[e]);
        fragWh[g][kf] = f;
      }

    f32x4 cst = {0.f, 0.f, 0.f, 0.f}, hhv = {0.f, 0.f, 0.f, 0.f};
    if (lrow < MBLK)
      cst = *(const f32x4*)&c0[(b0 + lrow) * HSZ + 16 * wv + 4 * lkg];

    __builtin_amdgcn_s_setprio(1);
    __syncthreads();   // (B): X produced g[0], g[1]; LDS staging visible

    f32x4 acc[4];
    {
      const float* gs = &gbuf[0][wv][0];
#pragma unroll
      for (int g = 0; g < 4; ++g)
        acc[g] = *(const f32x4*)&gs[((g * 4 + lkg) * 8 + lrow) * 4];
    }

    for (int t = 0; t < T_STEPS; ++t) {
      __builtin_amdgcn_s_barrier();
      asm volatile("" ::: "memory");

      const char* hbase = (const char*)hbuf + (t & 1) * 2048 + lrow * 128;
      const bf16x8 hB0 = *(const bf16x8*)(hbase + ((lkg * 16) ^ swz));
      const bf16x8 hB1 = *(const bf16x8*)(hbase + ((64 + lkg * 16) ^ swz));

      f32x4 cur[4];
#pragma unroll
      for (int g = 0; g < 4; ++g)
        cur[g] = __builtin_amdgcn_mfma_f32_16x16x32_bf16(fragWh[g][0], hB0, acc[g], 0, 0, 0);
#pragma unroll
      for (int g = 0; g < 4; ++g)
        cur[g] = __builtin_amdgcn_mfma_f32_16x16x32_bf16(fragWh[g][1], hB1, cur[g], 0, 0, 0);

      {
        const float* gs = &gbuf[(t + 1) & 3][wv][0];
#pragma unroll
        for (int g = 0; g < 4; ++g)
          acc[g] = *(const f32x4*)&gs[((g * 4 + lkg) * 8 + lrow) * 4];
      }

      if (lrow < MBLK) {
        u16x4 pk;
#pragma unroll
        for (int e = 0; e < 4; ++e) {
          const float fg = fsig(cur[0][e]);
          const float ig = fsig(cur[1][e]);
          const float cd = ftanh2(cur[2][e]);
          const float og = fsig(cur[3][e]);
          const float c  = cst[e] * fg + cd * ig;
          cst[e] = c;
          hhv[e] = ftanh2(c) * og;
          pk[e] = f2bf_hw(hhv[e]);
        }
        *(u16x4*)((char*)hbuf + ((t + 1) & 1) * 2048 + lrow * 128 +
                  ((32 * wv + 8 * lkg) ^ swz)) = pk;
      }

      asm volatile("s_waitcnt lgkmcnt(0)" ::: "memory");
    }

    __builtin_amdgcn_s_barrier();   // epilogue (matches X's final out-proj round)
    if (lrow < MBLK) {
      *(f32x4*)&out[probs_elems + (size_t)(b0 + lrow) * HSZ + 16 * wv + 4 * lkg] = hhv;
      *(f32x4*)&out[probs_elems + (size_t)BATCH * HSZ +
                    (size_t)(b0 + lrow) * HSZ + 16 * wv + 4 * lkg] = cst;
    }
  } else {
    // ==== X-wave: DMA staging + x-GEMM + fused out-proj/softmax/probs store ===
    const int xw = wv - 4;
    const int hcolX = 16 * xw + lrow;

    bf16x8 fragWx[4][4];
#pragma unroll
    for (int g = 0; g < 4; ++g)
#pragma unroll
      for (int kf = 0; kf < 4; ++kf) {
        const float* p = Wg_[g] + hcolX * ZSZ + kf * 32 + 8 * lkg;
        bf16x8 f;
#pragma unroll
        for (int e = 0; e < 8; ++e) f[e] = (short)f2bf(p[e]);
        fragWx[g][kf] = f;
      }
    f32x4 biasV[4];
#pragma unroll
    for (int g = 0; g < 4; ++g)
      biasV[g] = *(const f32x4*)&bg_[g][16 * xw + 4 * lkg];

#define STAGE(TT, SLOT)                                                        \
    {                                                                          \
      const int tc = ((TT) < T_STEPS) ? (TT) : T_STEPS - 1;                    \
      const char* xb = (const char*)(x + (size_t)tc * BATCH * ISZ +            \
                                     (size_t)b0 * ISZ);                        \
      char* lb = (char*)&xbuf[SLOT][0];                                        \
      _Pragma("unroll")                                                        \
      for (int i = 0; i < 4; ++i) {                                            \
        const int row = 2 * i + (ln >> 5);                                     \
        const int sc = ((ln & 31) * 16) ^ ((row & 7) << 4);                    \
        stage16(xb + row * 512 + sc, lb + i * 1024);                           \
      }                                                                        \
    }

#define XPAIR(SE, SO, GE, GO)                                                  \
    {                                                                          \
      const char* xt = (const char*)&xbuf[(lrow & 8) ? (SO) : (SE)][0] +       \
                       (lrow & 7) * 512;                                       \
      f32x4 xacc[4];                                                           \
      _Pragma("unroll")                                                        \
      for (int g = 0; g < 4; ++g) xacc[g] = biasV[g];                          \
      _Pragma("unroll")                                                        \
      for (int kf = 0; kf < 4; ++kf) {                                         \
        const int cb = kf * 128 + lkg * 32;                                    \
        f32x4 a = *(const f32x4*)(xt + ((cb) ^ swz));                          \
        f32x4 b = *(const f32x4*)(xt + ((cb + 16) ^ swz));                     \
        bf16x8 f;                                                              \
        _Pragma("unroll")                                                      \
        for (int j = 0; j < 4; ++j) {                                          \
          f[j]     = (short)f2bf_hw(a[j]);                                     \
          f[4 + j] = (short)f2bf_hw(b[j]);                                     \
        }                                                                      \
        _Pragma("unroll")                                                      \
        for (int g = 0; g < 4; ++g)                                            \
          xacc[g] = __builtin_amdgcn_mfma_f32_16x16x32_bf16(                   \
              fragWx[g][kf], f, xacc[g], 0, 0, 0);                             \
      }                                                                        \
      float* gdst = (lrow & 8) ? &gbuf[GO][xw][0] : &gbuf[GE][xw][0];          \
      _Pragma("unroll")                                                        \
      for (int g = 0; g < 4; ++g)                                              \
        *(f32x4*)&gdst[((g * 4 + lkg) * 8 + (lrow & 7)) * 4] = xacc[g];        \
    }

// out-proj + softmax + probs store for h[R] -> probs row R-1 (kernel-B math).
// Reads hbuf slot R&1 during round R only (same window as P's own read).
#define OUTPROJ(R)                                                             \
    if ((R) > 0) {                                                             \
      const char* hb = (const char*)hbuf + ((R) & 1) * 2048 + lrow * 128;      \
      const bf16x8 hO0 = *(const bf16x8*)(hb + ((lkg * 16) ^ swz));            \
      const bf16x8 hO1 = *(const bf16x8*)(hb + ((64 + lkg * 16) ^ swz));       \
      f32x4 lac[8];                                                            \
      _Pragma("unroll")                                                        \
      for (int rf = 0; rf < 8; ++rf) {                                         \
        lac[rf] = *(const f32x4*)&bias_lds[16 * rf + 4 * lkg];                 \
        _Pragma("unroll")                                                      \
        for (int kf = 0; kf < 2; ++kf) {                                       \
          const bf16x8 wf = *(const bf16x8*)((const char*)wout_lds +           \
              (16 * rf + lrow) * 128 + ((kf * 64 + lkg * 16) ^ swz));          \
          lac[rf] = __builtin_amdgcn_mfma_f32_16x16x32_bf16(                   \
              wf, kf ? hO1 : hO0, lac[rf], 0, 0, 0);                           \
        }                                                                      \
      }                                                                        \
      float m = -1e30f;                                                        \
      _Pragma("unroll")                                                        \
      for (int rf = 0; rf < 8; ++rf)                                           \
        _Pragma("unroll")                                                      \
        for (int e = 0; e < 4; ++e) m = fmaxf(m, lac[rf][e]);                  \
      m = fmaxf(m, __shfl_xor(m, 16));                                         \
      m = fmaxf(m, __shfl_xor(m, 32));                                         \
      float s = 0.0f;                                                          \
      _Pragma("unroll")                                                        \
      for (int rf = 0; rf < 8; ++rf)                                           \
        _Pragma("unroll")                                                      \
        for (int e = 0; e < 4; ++e) {                                          \
          float p = __expf(lac[rf][e] - m);                                    \
          lac[rf][e] = p;                                                      \
          s += p;                                                              \
        }                                                                      \
      s += __shfl_xor(s, 16);                                                  \
      s += __shfl_xor(s, 32);                                                  \
      const float inv = 1.0f / s;                                              \
      if (lrow < MBLK) {                                                       \
        float* orow = &out[(size_t)((R) - 1) * BATCH * VSZ +                   \
                           (size_t)(b0 + lrow) * VSZ];                         \
        _Pragma("unroll")                                                      \
        for (int rf = 0; rf < 8; ++rf) {                                       \
          f32x4 pv = lac[rf] * inv;                                            \
          *(f32x4*)&orow[16 * rf + 4 * lkg] = pv;                              \
        }                                                                      \
      }                                                                        \
    }

    // prologue: stage tiles 0..6; produce g[0], g[1]
    STAGE(0, 0) STAGE(1, 1) STAGE(2, 2) STAGE(3, 3)
    STAGE(4, 4) STAGE(5, 5) STAGE(6, 6)
    asm volatile("s_waitcnt vmcnt(20)" ::: "memory");   // tiles 0,1 landed
    __builtin_amdgcn_sched_barrier(0);
    XPAIR(0, 1, 0, 1)
    asm volatile("s_waitcnt lgkmcnt(0)" ::: "memory");
    __syncthreads();   // (B)

    for (int t = 0; t < T_STEPS; t += 2) {
      const int s2 = (t + 2) % 7, s3 = (t + 3) % 7;
      const int s7 = (t + 7) % 7, s8 = (t + 8) % 7;
      const int g2 = (t + 2) & 3, g3 = (t + 3) & 3;

      // even round t: stage t+7; produce pair (t+2,t+3); out-proj h[t]
      __builtin_amdgcn_s_barrier();
      asm volatile("" ::: "memory");
      STAGE(t + 7, s7)
      // tiles t+2,t+3 staged >=4 rounds ago; younger ops = 3 rounds x (4 DMA
      // + 8 probs stores) + this round's 4 DMA = 40 -> counted, never drains.
      asm volatile("s_waitcnt vmcnt(40)" ::: "memory");
      __builtin_amdgcn_sched_barrier(0);
      XPAIR(s2, s3, g2, g3)
      OUTPROJ(t)
      asm volatile("s_waitcnt lgkmcnt(0)" ::: "memory");

      // odd round t+1: stage t+8; out-proj h[t+1]
      __builtin_amdgcn_s_barrier();
      asm volatile("" ::: "memory");
      STAGE(t + 8, s8)
      OUTPROJ(t + 1)
      asm volatile("s_waitcnt lgkmcnt(0)" ::: "memory");
    }

    __builtin_amdgcn_s_barrier();   // epilogue: h[512] visible
    OUTPROJ(T_STEPS)                // -> probs row 511
#undef OUTPROJ
#undef XPAIR
#undef STAGE
  }
}

extern "C" void kernel_launch(void* const* d_in, const int* in_sizes, int n_in,
                              void* d_out, int out_size, void* d_ws, size_t ws_size,
                              hipStream_t stream) {
  const float* x    = (const float*)d_in[0];
  const float* h0   = (const float*)d_in[1];
  const float* c0   = (const float*)d_in[2];
  const float* Wf   = (const float*)d_in[3];
  const float* bf_  = (const float*)d_in[4];
  const float* Wif  = (const float*)d_in[5];
  const float* bif_ = (const float*)d_in[6];
  const float* Wic  = (const float*)d_in[7];
  const float* bic_ = (const float*)d_in[8];
  const float* Wo   = (const float*)d_in[9];
  const float* bo_  = (const float*)d_in[10];
  const float* Wout = (const float*)d_in[11];
  const float* bout = (const float*)d_in[12];
  float* out = (float*)d_out;

  hipLaunchKernelGGL(lstm_rec, dim3(BATCH / MBLK), dim3(ATHREADS), 0, stream,
                     x, h0, c0, Wf, bf_, Wif, bif_, Wic, bic_, Wo, bo_,
                     Wout, bout, out);
}

// Round 15
// 584.759 us; speedup vs baseline: 1.5258x; 1.5258x over previous
//
#include <hip/hip_runtime.h>
#include <hip/hip_bf16.h>

#define T_STEPS 512
#define BATCH   2048
#define ISZ     128
#define HSZ     64
#define VSZ     128
#define ZSZ     192   // I + H

#define MBLK    8     // batch rows per recurrence block -> 256 blocks
#define ATHREADS 512  // 4 P-waves + 4 X-waves
#define L2E     1.44269504f

typedef __attribute__((ext_vector_type(8))) short bf16x8;
typedef __attribute__((ext_vector_type(4))) float f32x4;
typedef __attribute__((ext_vector_type(4))) unsigned short u16x4;

__device__ __forceinline__ unsigned short f2bf(float x) {
  union { float f; unsigned int u; } v; v.f = x;
  unsigned int u = v.u;
  unsigned int r = (u + 0x7fffu + ((u >> 16) & 1u)) >> 16;  // RNE
  return (unsigned short)r;
}

__device__ __forceinline__ unsigned short f2bf_hw(float x) {
  __hip_bfloat16 b = __float2bfloat16(x);
  return *reinterpret_cast<unsigned short*>(&b);
}

// activations on PRE-SCALED inputs: y_sig = -x*log2e, y_tanh = -2x*log2e
__device__ __forceinline__ float fsig2(float y) {   // sigmoid(x)
  return __builtin_amdgcn_rcpf(1.0f + __builtin_exp2f(y));
}
__device__ __forceinline__ float ftanh2s(float y) { // tanh(x)
  return __builtin_amdgcn_rcpf(1.0f + __builtin_exp2f(y)) * 2.0f - 1.0f;
}

__device__ __forceinline__ void stage16(const void* g, void* l) {
  __builtin_amdgcn_global_load_lds(
      (const __attribute__((address_space(1))) void*)g,
      (__attribute__((address_space(3))) void*)l, 16, 0, 0);
}

// ======== Kernel A: lockstep rounds — P (h-chain) + X (DMA + time-packed x-GEMM)
__global__ __launch_bounds__(ATHREADS, 1) void lstm_rec(
    const float* __restrict__ x,
    const float* __restrict__ h0,
    const float* __restrict__ c0,
    const float* __restrict__ Wf,  const float* __restrict__ bf_,
    const float* __restrict__ Wif, const float* __restrict__ bif_,
    const float* __restrict__ Wic, const float* __restrict__ bic_,
    const float* __restrict__ Wo,  const float* __restrict__ bo_,
    float* __restrict__ out)
{
  // gbuf[slot4][xw4][(g*4+lkg)16][col8][4e] f32 — SCALED pre-acts, bias added
  __shared__ __attribute__((aligned(16))) float gbuf[4][4][512];
  // xbuf: 5-slot ring of x tiles [8 rows][512B], swizzled content (DMA-staged)
  __shared__ __attribute__((aligned(16))) float xbuf[5][1024];
  // hbuf: [slot2][row16][col64] bf16, XOR-swizzled ((row&7)<<4 on bytes)
  __shared__ __attribute__((aligned(16))) unsigned short hbuf[2 * 16 * 64];

  const int tid  = threadIdx.x;
  const int wv   = tid >> 6;     // 0..3 = P, 4..7 = X
  const int ln   = tid & 63;
  const int lrow = ln & 15;
  const int lkg  = ln >> 4;
  const int b0   = blockIdx.x * MBLK;
  const int swz  = (lrow & 7) << 4;

  // per-gate prescale: sigmoid gates -log2e; candidate (tanh) -2log2e
  const float gsc[4] = {-L2E, -L2E, -2.0f * L2E, -L2E};

  // zero hbuf (rows 8..15 stay zero forever)
  for (int i = tid; i < 2 * 16 * 64; i += ATHREADS) hbuf[i] = 0;
  __syncthreads();
  if (tid < 128) {   // stage h0 rows 0..7, swizzled, packed b64
    const int r = tid >> 4, cb = tid & 15;
    f32x4 hv = *(const f32x4*)&h0[(b0 + r) * HSZ + cb * 4];
    u16x4 pk;
#pragma unroll
    for (int j = 0; j < 4; ++j) pk[j] = f2bf(hv[j]);
    *(u16x4*)((char*)hbuf + r * 128 + ((cb * 8) ^ ((r & 7) << 4))) = pk;
  }

  const float* Wg_[4] = {Wf, Wif, Wic, Wo};
  const float* bg_[4] = {bf_, bif_, bic_, bo_};
  const size_t probs_elems = (size_t)T_STEPS * BATCH * VSZ;

  if (wv < 4) {
    // ========== P-wave: minimal h-chain, transposed-C cell update ==========
    const int hcol = 16 * wv + lrow;   // fragWh A-row

    bf16x8 fragWh[4][2];               // A: gsc[g]*W[g][16wv+lrow][128+kf*32+8lkg+j]
#pragma unroll
    for (int g = 0; g < 4; ++g)
#pragma unroll
      for (int kf = 0; kf < 2; ++kf) {
        const float* p = Wg_[g] + hcol * ZSZ + ISZ + kf * 32 + 8 * lkg;
        bf16x8 f;
#pragma unroll
        for (int e = 0; e < 8; ++e) f[e] = (short)f2bf(p[e] * gsc[g]);
        fragWh[g][kf] = f;
      }

    // cell state: lane(lkg,lrow) owns batch row lrow (<8), hcols 16wv+4lkg+e
    f32x4 cst = {0.f, 0.f, 0.f, 0.f}, hhv = {0.f, 0.f, 0.f, 0.f};
    if (lrow < MBLK)
      cst = *(const f32x4*)&c0[(b0 + lrow) * HSZ + 16 * wv + 4 * lkg];

    unsigned short* hout16 = (unsigned short*)out;
    __builtin_amdgcn_s_setprio(1);
    __syncthreads();   // (B): X produced g[0], g[1]

    // preload acc = g[0] (slot 0)
    f32x4 acc[4];
    {
      const float* gs = &gbuf[0][wv][0];
#pragma unroll
      for (int g = 0; g < 4; ++g)
        acc[g] = *(const f32x4*)&gs[((g * 4 + lkg) * 8 + lrow) * 4];
    }

    for (int t = 0; t < T_STEPS; ++t) {
      __builtin_amdgcn_s_barrier();
      asm volatile("" ::: "memory");

      // h[t] B-fragments (z^T) — issue together with next-g preload (one
      // LDS latency window; MFMAs only wait on the first two reads)
      const char* hbase = (const char*)hbuf + (t & 1) * 2048 + lrow * 128;
      const bf16x8 hB0 = *(const bf16x8*)(hbase + ((lkg * 16) ^ swz));
      const bf16x8 hB1 = *(const bf16x8*)(hbase + ((64 + lkg * 16) ^ swz));
      f32x4 nxt[4];
      {
        const float* gs = &gbuf[(t + 1) & 3][wv][0];
#pragma unroll
        for (int g = 0; g < 4; ++g)
          nxt[g] = *(const f32x4*)&gs[((g * 4 + lkg) * 8 + lrow) * 4];
      }

      f32x4 cur[4];
#pragma unroll
      for (int g = 0; g < 4; ++g)
        cur[g] = __builtin_amdgcn_mfma_f32_16x16x32_bf16(fragWh[g][0], hB0, acc[g], 0, 0, 0);
#pragma unroll
      for (int g = 0; g < 4; ++g)
        cur[g] = __builtin_amdgcn_mfma_f32_16x16x32_bf16(fragWh[g][1], hB1, cur[g], 0, 0, 0);
#pragma unroll
      for (int g = 0; g < 4; ++g) acc[g] = nxt[g];

      // cell update: fully in-lane, lanes lrow<8 (scaled pre-acts)
      if (lrow < MBLK) {
        u16x4 pk;
#pragma unroll
        for (int e = 0; e < 4; ++e) {
          const float fg = fsig2(cur[0][e]);
          const float ig = fsig2(cur[1][e]);
          const float cd = ftanh2s(cur[2][e]);
          const float og = fsig2(cur[3][e]);
          const float c  = cst[e] * fg + cd * ig;
          cst[e] = c;
          hhv[e] = ftanh2s(c * (-2.0f * L2E)) * og;
          pk[e] = f2bf_hw(hhv[e]);
        }
        // publish h[t+1]: one swizzled b64 LDS write + one b64 global stash
        *(u16x4*)((char*)hbuf + ((t + 1) & 1) * 2048 + lrow * 128 +
                  ((32 * wv + 8 * lkg) ^ swz)) = pk;
        *(u16x4*)&hout16[((size_t)t * BATCH + b0 + lrow) * (2 * VSZ) +
                         16 * wv + 4 * lkg] = pk;
      }

      asm volatile("s_waitcnt lgkmcnt(0)" ::: "memory");
    }

    // final h/c outputs
    if (lrow < MBLK) {
      *(f32x4*)&out[probs_elems + (size_t)(b0 + lrow) * HSZ + 16 * wv + 4 * lkg] = hhv;
      *(f32x4*)&out[probs_elems + (size_t)BATCH * HSZ +
                    (size_t)(b0 + lrow) * HSZ + 16 * wv + 4 * lkg] = cst;
    }
  } else {
    // ========== X-wave: DMA x + time-packed x-GEMM (pairs), 2+ rounds ahead ==
    const int xw = wv - 4;
    const int hcolX = 16 * xw + lrow;

    bf16x8 fragWx[4][4];               // A: gsc[g]*W[g][16xw+lrow][kf*32+8lkg+j]
#pragma unroll
    for (int g = 0; g < 4; ++g)
#pragma unroll
      for (int kf = 0; kf < 4; ++kf) {
        const float* p = Wg_[g] + hcolX * ZSZ + kf * 32 + 8 * lkg;
        bf16x8 f;
#pragma unroll
        for (int e = 0; e < 8; ++e) f[e] = (short)f2bf(p[e] * gsc[g]);
        fragWx[g][kf] = f;
      }
    f32x4 biasV[4];                    // scaled bias: C rows 4lkg+e
#pragma unroll
    for (int g = 0; g < 4; ++g) {
      f32x4 b = *(const f32x4*)&bg_[g][16 * xw + 4 * lkg];
      biasV[g] = b * gsc[g];
    }

    const int rowx = min(b0 + lrow, BATCH - 1);

// DMA one x tile (8 rows x 512B) into xbuf[SLOT], pre-swizzled source
#define STAGE(TT, SLOT)                                                        \
    {                                                                          \
      const int tc = ((TT) < T_STEPS) ? (TT) : T_STEPS - 1;                    \
      const char* xb = (const char*)(x + (size_t)tc * BATCH * ISZ +            \
                                     (size_t)b0 * ISZ);                        \
      char* lb = (char*)&xbuf[SLOT][0];                                        \
      _Pragma("unroll")                                                        \
      for (int i = 0; i < 4; ++i) {                                            \
        const int row = 2 * i + (ln >> 5);                                     \
        const int sc = ((ln & 31) * 16) ^ ((row & 7) << 4);                    \
        stage16(xb + row * 512 + sc, lb + i * 1024);                           \
      }                                                                        \
    }

// produce pair g[.] even-slot SE / odd-slot SO (tiles), gbuf slots GE / GO
#define XPAIR(SE, SO, GE, GO)                                                  \
    {                                                                          \
      const char* xt = (const char*)&xbuf[(lrow & 8) ? (SO) : (SE)][0] +       \
                       (lrow & 7) * 512;                                       \
      f32x4 xacc[4];                                                           \
      _Pragma("unroll")                                                        \
      for (int g = 0; g < 4; ++g) xacc[g] = biasV[g];                          \
      _Pragma("unroll")                                                        \
      for (int kf = 0; kf < 4; ++kf) {                                         \
        const int cb = kf * 128 + lkg * 32;                                    \
        f32x4 a = *(const f32x4*)(xt + ((cb) ^ swz));                          \
        f32x4 b = *(const f32x4*)(xt + ((cb + 16) ^ swz));                     \
        bf16x8 f;                                                              \
        _Pragma("unroll")                                                      \
        for (int j = 0; j < 4; ++j) {                                          \
          f[j]     = (short)f2bf_hw(a[j]);                                     \
          f[4 + j] = (short)f2bf_hw(b[j]);                                     \
        }                                                                      \
        _Pragma("unroll")                                                      \
        for (int g = 0; g < 4; ++g)                                            \
          xacc[g] = __builtin_amdgcn_mfma_f32_16x16x32_bf16(                   \
              fragWx[g][kf], f, xacc[g], 0, 0, 0);                             \
      }                                                                        \
      float* gdst = (lrow & 8) ? &gbuf[GO][xw][0] : &gbuf[GE][xw][0];          \
      _Pragma("unroll")                                                        \
      for (int g = 0; g < 4; ++g)                                              \
        *(f32x4*)&gdst[((g * 4 + lkg) * 8 + (lrow & 7)) * 4] = xacc[g];        \
    }

    // prologue: stage tiles 0..4; produce g[0],g[1] (cols packed by parity)
    STAGE(0, 0) STAGE(1, 1) STAGE(2, 2) STAGE(3, 3) STAGE(4, 4)
    asm volatile("s_waitcnt vmcnt(12)" ::: "memory");   // tiles 0,1 landed
    __builtin_amdgcn_sched_barrier(0);
    XPAIR(0, 1, 0, 1)
    asm volatile("s_waitcnt lgkmcnt(0)" ::: "memory");
    __syncthreads();   // (B)

    int stg = 0;   // xbuf slot staged this round
    int rs  = 2;   // xbuf slot holding tile t+2 at even-round top
    int gw  = 2;   // gbuf slot for g[t+2]
    for (int t = 0; t < T_STEPS; t += 2) {
      // even round: stage + produce pair (t+2, t+3)
      __builtin_amdgcn_s_barrier();
      asm volatile("" ::: "memory");
      STAGE(t + 5, stg)
      stg = (stg == 4) ? 0 : stg + 1;
      asm volatile("s_waitcnt vmcnt(8)" ::: "memory");  // tiles t+2,t+3 landed
      __builtin_amdgcn_sched_barrier(0);
      {
        const int rs1 = (rs == 4) ? 0 : rs + 1;
        XPAIR(rs, rs1, gw, (gw + 1) & 3)
        rs = (rs1 == 4) ? 0 : rs1 + 1;
        gw = (gw + 2) & 3;
      }
      asm volatile("s_waitcnt lgkmcnt(0)" ::: "memory");

      // odd round: stage only
      __builtin_amdgcn_s_barrier();
      asm volatile("" ::: "memory");
      STAGE(t + 6, stg)
      stg = (stg == 4) ? 0 : stg + 1;
    }
#undef XPAIR
#undef STAGE
  }
}

// ========== Kernel B: out-proj + softmax, fully parallel over T x B ==========
#define BBLOCKS 2048
__global__ __launch_bounds__(256) void lstm_out(
    const float* __restrict__ Wout, const float* __restrict__ bout_,
    float* __restrict__ out)
{
  const int tid  = threadIdx.x;
  const int wv   = tid >> 6;
  const int ln   = tid & 63;
  const int lrow = ln & 15;
  const int lkg  = ln >> 4;

  bf16x8 fragWo[8][2];
#pragma unroll
  for (int rf = 0; rf < 8; ++rf)
#pragma unroll
    for (int kf = 0; kf < 2; ++kf) {
      const float* p = Wout + (16 * rf + lrow) * HSZ + kf * 32 + 8 * lkg;
      bf16x8 f;
#pragma unroll
      for (int e = 0; e < 8; ++e) f[e] = (short)f2bf(p[e]);
      fragWo[rf][kf] = f;
    }
  f32x4 boV[8];
#pragma unroll
  for (int rf = 0; rf < 8; ++rf) boV[rf] = *(const f32x4*)&bout_[16 * rf + 4 * lkg];

  const unsigned short* hin = (const unsigned short*)out;
  const int NT = T_STEPS * (BATCH / 16);
  const int nw = BBLOCKS * 4;

  for (int tile = blockIdx.x * 4 + wv; tile < NT; tile += nw) {
    const int t  = tile >> 7;
    const int b0 = (tile & 127) * 16;

    const unsigned short* hr = hin + ((size_t)t * BATCH + b0 + lrow) * (2 * VSZ);
    const bf16x8 hb0 = *(const bf16x8*)&hr[8 * lkg];
    const bf16x8 hb1 = *(const bf16x8*)&hr[32 + 8 * lkg];

    f32x4 lac[8];
#pragma unroll
    for (int rf = 0; rf < 8; ++rf) {
      lac[rf] = boV[rf];
      lac[rf] = __builtin_amdgcn_mfma_f32_16x16x32_bf16(fragWo[rf][0], hb0, lac[rf], 0, 0, 0);
      lac[rf] = __builtin_amdgcn_mfma_f32_16x16x32_bf16(fragWo[rf][1], hb1, lac[rf], 0, 0, 0);
    }

    float m = -1e30f;
#pragma unroll
    for (int rf = 0; rf < 8; ++rf)
#pragma unroll
      for (int e = 0; e < 4; ++e) m = fmaxf(m, lac[rf][e]);
    m = fmaxf(m, __shfl_xor(m, 16));
    m = fmaxf(m, __shfl_xor(m, 32));
    float s = 0.0f;
#pragma unroll
    for (int rf = 0; rf < 8; ++rf)
#pragma unroll
      for (int e = 0; e < 4; ++e) {
        float p = __expf(lac[rf][e] - m);
        lac[rf][e] = p;
        s += p;
      }
    s += __shfl_xor(s, 16);
    s += __shfl_xor(s, 32);
    const float inv = 1.0f / s;

    float* orow = &out[((size_t)t * BATCH + b0 + lrow) * VSZ];
#pragma unroll
    for (int rf = 0; rf < 8; ++rf) {
      f32x4 pv = lac[rf] * inv;
      *(f32x4*)&orow[16 * rf + 4 * lkg] = pv;
    }
  }
}

extern "C" void kernel_launch(void* const* d_in, const int* in_sizes, int n_in,
                              void* d_out, int out_size, void* d_ws, size_t ws_size,
                              hipStream_t stream) {
  const float* x    = (const float*)d_in[0];
  const float* h0   = (const float*)d_in[1];
  const float* c0   = (const float*)d_in[2];
  const float* Wf   = (const float*)d_in[3];
  const float* bf_  = (const float*)d_in[4];
  const float* Wif  = (const float*)d_in[5];
  const float* bif_ = (const float*)d_in[6];
  const float* Wic  = (const float*)d_in[7];
  const float* bic_ = (const float*)d_in[8];
  const float* Wo   = (const float*)d_in[9];
  const float* bo_  = (const float*)d_in[10];
  const float* Wout = (const float*)d_in[11];
  const float* bout = (const float*)d_in[12];
  float* out = (float*)d_out;

  hipLaunchKernelGGL(lstm_rec, dim3(BATCH / MBLK), dim3(ATHREADS), 0, stream,
                     x, h0, c0, Wf, bf_, Wif, bif_, Wic, bic_, Wo, bo_, out);
  hipLaunchKernelGGL(lstm_out, dim3(BBLOCKS), dim3(256), 0, stream,
                     Wout, bout, out);
}

// Round 16
// 503.752 us; speedup vs baseline: 1.7712x; 1.1608x over previous
//
#include <hip/hip_runtime.h>
#include <hip/hip_bf16.h>

#define T_STEPS 512
#define BATCH   2048
#define ISZ     128
#define HSZ     64
#define VSZ     128
#define ZSZ     192   // I + H

#define MBLK    8     // batch rows per block -> 256 blocks
#define ATHREADS 768  // 4 P + 4 X + 4 O waves (1P+1X+1O per SIMD)

typedef __attribute__((ext_vector_type(8))) short bf16x8;
typedef __attribute__((ext_vector_type(4))) float f32x4;
typedef __attribute__((ext_vector_type(4))) unsigned short u16x4;

__device__ __forceinline__ unsigned short f2bf(float x) {
  union { float f; unsigned int u; } v; v.f = x;
  unsigned int u = v.u;
  unsigned int r = (u + 0x7fffu + ((u >> 16) & 1u)) >> 16;  // RNE
  return (unsigned short)r;
}

__device__ __forceinline__ unsigned short f2bf_hw(float x) {
  __hip_bfloat16 b = __float2bfloat16(x);
  return *reinterpret_cast<unsigned short*>(&b);
}

// branch-free, NaN-safe at +/-inf (validated rounds 8-13; r10 form)
__device__ __forceinline__ float fsig(float x) {
  float e = __expf(-x);
  return __builtin_amdgcn_rcpf(1.0f + e);
}
__device__ __forceinline__ float ftanh2(float x) {
  float e = __expf(-2.0f * x);
  return __builtin_amdgcn_rcpf(1.0f + e) * 2.0f - 1.0f;
}

__device__ __forceinline__ void stage16(const void* g, void* l) {
  __builtin_amdgcn_global_load_lds(
      (const __attribute__((address_space(1))) void*)g,
      (__attribute__((address_space(3))) void*)l, 16, 0, 0);
}

// ==== Fully fused: P (h-chain) + X (DMA + x-GEMM) + O (out-proj/softmax) =====
__global__ __launch_bounds__(ATHREADS, 1) void lstm_fused(
    const float* __restrict__ x,
    const float* __restrict__ h0,
    const float* __restrict__ c0,
    const float* __restrict__ Wf,  const float* __restrict__ bf_,
    const float* __restrict__ Wif, const float* __restrict__ bif_,
    const float* __restrict__ Wic, const float* __restrict__ bic_,
    const float* __restrict__ Wo,  const float* __restrict__ bo_,
    const float* __restrict__ Wout, const float* __restrict__ bout_,
    float* __restrict__ out)
{
  // gbuf: r9-validated conflict-free stride (256B per (g*4+lkg) row); 64KB
  __shared__ __attribute__((aligned(16))) float gbuf[4][4][1024];
  // xbuf: 5-slot ring of x tiles [8 rows][512B], swizzled content; 20KB
  __shared__ __attribute__((aligned(16))) float xbuf[5][1024];
  // hbuf: 8-slot ring [16 rows][64 cols] bf16, XOR-swizzled; 16KB
  __shared__ __attribute__((aligned(16))) unsigned short hbuf[8 * 16 * 64];

  const int tid  = threadIdx.x;
  const int wv   = tid >> 6;     // 0..3 = P, 4..7 = X, 8..11 = O
  const int ln   = tid & 63;
  const int lrow = ln & 15;
  const int lkg  = ln >> 4;
  const int b0   = blockIdx.x * MBLK;
  const int swz  = (lrow & 7) << 4;

  // zero hbuf (rows 8..15 of every slot stay zero forever)
  for (int i = tid; i < 8 * 16 * 64; i += ATHREADS) hbuf[i] = 0;
  __syncthreads();
  if (tid < 128) {   // stage h0 into slot 0, rows 0..7, swizzled b64
    const int r = tid >> 4, cb = tid & 15;
    f32x4 hv = *(const f32x4*)&h0[(b0 + r) * HSZ + cb * 4];
    u16x4 pk;
#pragma unroll
    for (int j = 0; j < 4; ++j) pk[j] = f2bf(hv[j]);
    *(u16x4*)((char*)hbuf + r * 128 + ((cb * 8) ^ ((r & 7) << 4))) = pk;
  }

  const float* Wg_[4] = {Wf, Wif, Wic, Wo};
  const float* bg_[4] = {bf_, bif_, bic_, bo_};
  const size_t probs_elems = (size_t)T_STEPS * BATCH * VSZ;

  if (wv < 4) {
    // ========== P-wave: minimal h-chain (r10 form; ring + padded gbuf) ======
    const int hcol = 16 * wv + lrow;

    bf16x8 fragWh[4][2];
#pragma unroll
    for (int g = 0; g < 4; ++g)
#pragma unroll
      for (int kf = 0; kf < 2; ++kf) {
        const float* p = Wg_[g] + hcol * ZSZ + ISZ + kf * 32 + 8 * lkg;
        bf16x8 f;
#pragma unroll
        for (int e = 0; e < 8; ++e) f[e] = (short)f2bf(p[e]);
        fragWh[g][kf] = f;
      }

    f32x4 cst = {0.f, 0.f, 0.f, 0.f}, hhv = {0.f, 0.f, 0.f, 0.f};
    if (lrow < MBLK)
      cst = *(const f32x4*)&c0[(b0 + lrow) * HSZ + 16 * wv + 4 * lkg];

    __builtin_amdgcn_s_setprio(1);
    __syncthreads();   // (B): X produced g[0], g[1]

    f32x4 acc[4];
    {
      const float* gs = &gbuf[0][wv][0];
#pragma unroll
      for (int g = 0; g < 4; ++g)
        acc[g] = *(const f32x4*)&gs[(g * 4 + lkg) * 64 + lrow * 4];
    }

    for (int t = 0; t < T_STEPS; ++t) {
      __builtin_amdgcn_s_barrier();
      asm volatile("" ::: "memory");

      const char* hbase = (const char*)hbuf + (t & 7) * 2048 + lrow * 128;
      const bf16x8 hB0 = *(const bf16x8*)(hbase + ((lkg * 16) ^ swz));
      const bf16x8 hB1 = *(const bf16x8*)(hbase + ((64 + lkg * 16) ^ swz));

      f32x4 cur[4];
#pragma unroll
      for (int g = 0; g < 4; ++g)
        cur[g] = __builtin_amdgcn_mfma_f32_16x16x32_bf16(fragWh[g][0], hB0, acc[g], 0, 0, 0);
#pragma unroll
      for (int g = 0; g < 4; ++g)
        cur[g] = __builtin_amdgcn_mfma_f32_16x16x32_bf16(fragWh[g][1], hB1, cur[g], 0, 0, 0);

      // preload next round's x-part acc (written by X >=1 barrier ago)
      {
        const float* gs = &gbuf[(t + 1) & 3][wv][0];
#pragma unroll
        for (int g = 0; g < 4; ++g)
          acc[g] = *(const f32x4*)&gs[(g * 4 + lkg) * 64 + lrow * 4];
      }

      // cell update: fully in-lane, lanes lrow<8
      if (lrow < MBLK) {
        u16x4 pk;
#pragma unroll
        for (int e = 0; e < 4; ++e) {
          const float fg = fsig(cur[0][e]);
          const float ig = fsig(cur[1][e]);
          const float cd = ftanh2(cur[2][e]);
          const float og = fsig(cur[3][e]);
          const float c  = cst[e] * fg + cd * ig;
          cst[e] = c;
          hhv[e] = ftanh2(c) * og;
          pk[e] = f2bf_hw(hhv[e]);
        }
        // publish h[t+1] to ring slot (t+1)&7 (LDS only; O consumes from LDS)
        *(u16x4*)((char*)hbuf + ((t + 1) & 7) * 2048 + lrow * 128 +
                  ((32 * wv + 8 * lkg) ^ swz)) = pk;
      }

      asm volatile("s_waitcnt lgkmcnt(0)" ::: "memory");
    }

    __builtin_amdgcn_s_barrier();   // final (matches X/O epilogue)
    if (lrow < MBLK) {
      *(f32x4*)&out[probs_elems + (size_t)(b0 + lrow) * HSZ + 16 * wv + 4 * lkg] = hhv;
      *(f32x4*)&out[probs_elems + (size_t)BATCH * HSZ +
                    (size_t)(b0 + lrow) * HSZ + 16 * wv + 4 * lkg] = cst;
    }
  } else if (wv < 8) {
    // ========== X-wave: DMA x + time-packed x-GEMM (r10 form, padded gbuf) ===
    const int xw = wv - 4;
    const int hcolX = 16 * xw + lrow;

    bf16x8 fragWx[4][4];
#pragma unroll
    for (int g = 0; g < 4; ++g)
#pragma unroll
      for (int kf = 0; kf < 4; ++kf) {
        const float* p = Wg_[g] + hcolX * ZSZ + kf * 32 + 8 * lkg;
        bf16x8 f;
#pragma unroll
        for (int e = 0; e < 8; ++e) f[e] = (short)f2bf(p[e]);
        fragWx[g][kf] = f;
      }
    f32x4 biasV[4];
#pragma unroll
    for (int g = 0; g < 4; ++g)
      biasV[g] = *(const f32x4*)&bg_[g][16 * xw + 4 * lkg];

#define STAGE(TT, SLOT)                                                        \
    {                                                                          \
      const int tc = ((TT) < T_STEPS) ? (TT) : T_STEPS - 1;                    \
      const char* xb = (const char*)(x + (size_t)tc * BATCH * ISZ +            \
                                     (size_t)b0 * ISZ);                        \
      char* lb = (char*)&xbuf[SLOT][0];                                        \
      _Pragma("unroll")                                                        \
      for (int i = 0; i < 4; ++i) {                                            \
        const int row = 2 * i + (ln >> 5);                                     \
        const int sc = ((ln & 31) * 16) ^ ((row & 7) << 4);                    \
        stage16(xb + row * 512 + sc, lb + i * 1024);                           \
      }                                                                        \
    }

#define XPAIR(SE, SO, GE, GO)                                                  \
    {                                                                          \
      const char* xt = (const char*)&xbuf[(lrow & 8) ? (SO) : (SE)][0] +       \
                       (lrow & 7) * 512;                                       \
      f32x4 xacc[4];                                                           \
      _Pragma("unroll")                                                        \
      for (int g = 0; g < 4; ++g) xacc[g] = biasV[g];                          \
      _Pragma("unroll")                                                        \
      for (int kf = 0; kf < 4; ++kf) {                                         \
        const int cb = kf * 128 + lkg * 32;                                    \
        f32x4 a = *(const f32x4*)(xt + ((cb) ^ swz));                          \
        f32x4 b = *(const f32x4*)(xt + ((cb + 16) ^ swz));                     \
        bf16x8 f;                                                              \
        _Pragma("unroll")                                                      \
        for (int j = 0; j < 4; ++j) {                                          \
          f[j]     = (short)f2bf_hw(a[j]);                                     \
          f[4 + j] = (short)f2bf_hw(b[j]);                                     \
        }                                                                      \
        _Pragma("unroll")                                                      \
        for (int g = 0; g < 4; ++g)                                            \
          xacc[g] = __builtin_amdgcn_mfma_f32_16x16x32_bf16(                   \
              fragWx[g][kf], f, xacc[g], 0, 0, 0);                             \
      }                                                                        \
      float* gdst = (lrow & 8) ? &gbuf[GO][xw][0] : &gbuf[GE][xw][0];          \
      _Pragma("unroll")                                                        \
      for (int g = 0; g < 4; ++g)                                              \
        *(f32x4*)&gdst[(g * 4 + lkg) * 64 + (lrow & 7) * 4] = xacc[g];         \
    }

    // prologue: stage tiles 0..4; produce g[0], g[1]
    STAGE(0, 0) STAGE(1, 1) STAGE(2, 2) STAGE(3, 3) STAGE(4, 4)
    asm volatile("s_waitcnt vmcnt(12)" ::: "memory");   // tiles 0,1 landed
    __builtin_amdgcn_sched_barrier(0);
    XPAIR(0, 1, 0, 1)
    asm volatile("s_waitcnt lgkmcnt(0)" ::: "memory");
    __syncthreads();   // (B)

    int stg = 0;   // xbuf slot staged this round
    int rs  = 2;   // xbuf slot holding tile t+2 at even-round top
    int gw  = 2;   // gbuf slot for g[t+2]
    for (int t = 0; t < T_STEPS; t += 2) {
      // even round: stage + produce pair (t+2, t+3)
      __builtin_amdgcn_s_barrier();
      asm volatile("" ::: "memory");
      STAGE(t + 5, stg)
      stg = (stg == 4) ? 0 : stg + 1;
      asm volatile("s_waitcnt vmcnt(8)" ::: "memory");  // tiles t+2,t+3 landed
      __builtin_amdgcn_sched_barrier(0);
      {
        const int rs1 = (rs == 4) ? 0 : rs + 1;
        XPAIR(rs, rs1, gw, (gw + 1) & 3)
        rs = (rs1 == 4) ? 0 : rs1 + 1;
        gw = (gw + 2) & 3;
      }
      asm volatile("s_waitcnt lgkmcnt(0)" ::: "memory");

      // odd round: stage only
      __builtin_amdgcn_s_barrier();
      asm volatile("" ::: "memory");
      STAGE(t + 6, stg)
      stg = (stg == 4) ? 0 : stg + 1;
    }
    __builtin_amdgcn_s_barrier();   // final
#undef XPAIR
#undef STAGE
  } else {
    // ========== O-wave: out-proj + softmax + probs store, 4-phase epochs =====
    const int o = wv - 8;

    bf16x8 fragWo[8][2];
#pragma unroll
    for (int rf = 0; rf < 8; ++rf)
#pragma unroll
      for (int kf = 0; kf < 2; ++kf) {
        const float* p = Wout + (16 * rf + lrow) * HSZ + kf * 32 + 8 * lkg;
        bf16x8 f;
#pragma unroll
        for (int e = 0; e < 8; ++e) f[e] = (short)f2bf(p[e]);
        fragWo[rf][kf] = f;
      }
    f32x4 boV[8];
#pragma unroll
    for (int rf = 0; rf < 8; ++rf) boV[rf] = *(const f32x4*)&bout_[16 * rf + 4 * lkg];

    __syncthreads();   // (B)

    f32x4 lac[8];
    bf16x8 hO0, hO1;
    float inv = 0.0f;

    for (int e = 0; e < 128; ++e) {
      const int tau = 4 * (e - 1) + 1 + o;   // h index this wave handles
      const bool act = (e > 0);

      // phase 0: h-frags + first 4 logit tiles
      __builtin_amdgcn_s_barrier();
      asm volatile("" ::: "memory");
      if (act) {
        const char* hb = (const char*)hbuf + (tau & 7) * 2048 + lrow * 128;
        hO0 = *(const bf16x8*)(hb + ((lkg * 16) ^ swz));
        hO1 = *(const bf16x8*)(hb + ((64 + lkg * 16) ^ swz));
#pragma unroll
        for (int rf = 0; rf < 4; ++rf) {
          lac[rf] = boV[rf];
          lac[rf] = __builtin_amdgcn_mfma_f32_16x16x32_bf16(fragWo[rf][0], hO0, lac[rf], 0, 0, 0);
          lac[rf] = __builtin_amdgcn_mfma_f32_16x16x32_bf16(fragWo[rf][1], hO1, lac[rf], 0, 0, 0);
        }
      }

      // phase 1: last 4 logit tiles
      __builtin_amdgcn_s_barrier();
      asm volatile("" ::: "memory");
      if (act) {
#pragma unroll
        for (int rf = 4; rf < 8; ++rf) {
          lac[rf] = boV[rf];
          lac[rf] = __builtin_amdgcn_mfma_f32_16x16x32_bf16(fragWo[rf][0], hO0, lac[rf], 0, 0, 0);
          lac[rf] = __builtin_amdgcn_mfma_f32_16x16x32_bf16(fragWo[rf][1], hO1, lac[rf], 0, 0, 0);
        }
      }

      // phase 2: softmax
      __builtin_amdgcn_s_barrier();
      asm volatile("" ::: "memory");
      if (act) {
        float m = -1e30f;
#pragma unroll
        for (int rf = 0; rf < 8; ++rf)
#pragma unroll
          for (int e2 = 0; e2 < 4; ++e2) m = fmaxf(m, lac[rf][e2]);
        m = fmaxf(m, __shfl_xor(m, 16));
        m = fmaxf(m, __shfl_xor(m, 32));
        float s = 0.0f;
#pragma unroll
        for (int rf = 0; rf < 8; ++rf)
#pragma unroll
          for (int e2 = 0; e2 < 4; ++e2) {
            float p = __expf(lac[rf][e2] - m);
            lac[rf][e2] = p;
            s += p;
          }
        s += __shfl_xor(s, 16);
        s += __shfl_xor(s, 32);
        inv = 1.0f / s;
      }

      // phase 3: probs store (row tau-1)
      __builtin_amdgcn_s_barrier();
      asm volatile("" ::: "memory");
      if (act && lrow < MBLK) {
        float* orow = &out[(size_t)(tau - 1) * BATCH * VSZ +
                           (size_t)(b0 + lrow) * VSZ];
#pragma unroll
        for (int rf = 0; rf < 8; ++rf) {
          f32x4 pv = lac[rf] * inv;
          *(f32x4*)&orow[16 * rf + 4 * lkg] = pv;
        }
      }
    }

    __builtin_amdgcn_s_barrier();   // final: h[509..512] all published
    // epilogue: full out-proj for tau = 509 + o  -> probs rows 508..511
    {
      const int tau = T_STEPS - 3 + o;
      const char* hb = (const char*)hbuf + (tau & 7) * 2048 + lrow * 128;
      const bf16x8 ha = *(const bf16x8*)(hb + ((lkg * 16) ^ swz));
      const bf16x8 hbv = *(const bf16x8*)(hb + ((64 + lkg * 16) ^ swz));
#pragma unroll
      for (int rf = 0; rf < 8; ++rf) {
        lac[rf] = boV[rf];
        lac[rf] = __builtin_amdgcn_mfma_f32_16x16x32_bf16(fragWo[rf][0], ha, lac[rf], 0, 0, 0);
        lac[rf] = __builtin_amdgcn_mfma_f32_16x16x32_bf16(fragWo[rf][1], hbv, lac[rf], 0, 0, 0);
      }
      float m = -1e30f;
#pragma unroll
      for (int rf = 0; rf < 8; ++rf)
#pragma unroll
        for (int e2 = 0; e2 < 4; ++e2) m = fmaxf(m, lac[rf][e2]);
      m = fmaxf(m, __shfl_xor(m, 16));
      m = fmaxf(m, __shfl_xor(m, 32));
      float s = 0.0f;
#pragma unroll
      for (int rf = 0; rf < 8; ++rf)
#pragma unroll
        for (int e2 = 0; e2 < 4; ++e2) {
          float p = __expf(lac[rf][e2] - m);
          lac[rf][e2] = p;
          s += p;
        }
      s += __shfl_xor(s, 16);
      s += __shfl_xor(s, 32);
      inv = 1.0f / s;
      if (lrow < MBLK) {
        float* orow = &out[(size_t)(tau - 1) * BATCH * VSZ +
                           (size_t)(b0 + lrow) * VSZ];
#pragma unroll
        for (int rf = 0; rf < 8; ++rf) {
          f32x4 pv = lac[rf] * inv;
          *(f32x4*)&orow[16 * rf + 4 * lkg] = pv;
        }
      }
    }
  }
}

extern "C" void kernel_launch(void* const* d_in, const int* in_sizes, int n_in,
                              void* d_out, int out_size, void* d_ws, size_t ws_size,
                              hipStream_t stream) {
  const float* x    = (const float*)d_in[0];
  const float* h0   = (const float*)d_in[1];
  const float* c0   = (const float*)d_in[2];
  const float* Wf   = (const float*)d_in[3];
  const float* bf_  = (const float*)d_in[4];
  const float* Wif  = (const float*)d_in[5];
  const float* bif_ = (const float*)d_in[6];
  const float* Wic  = (const float*)d_in[7];
  const float* bic_ = (const float*)d_in[8];
  const float* Wo   = (const float*)d_in[9];
  const float* bo_  = (const float*)d_in[10];
  const float* Wout = (const float*)d_in[11];
  const float* bout = (const float*)d_in[12];
  float* out = (float*)d_out;

  hipLaunchKernelGGL(lstm_fused, dim3(BATCH / MBLK), dim3(ATHREADS), 0, stream,
                     x, h0, c0, Wf, bf_, Wif, bif_, Wic, bic_, Wo, bo_,
                     Wout, bout, out);
}